// Round 5
// baseline (306.931 us; speedup 1.0000x reference)
//
#include <hip/hip_runtime.h>
#include <cstdint>
#include <cstddef>

#define B_ 512
#define W_ 1024
#define L_ 64
#define J_ 8
#define I_ 32
#define O_ 128

// ws layout (floats):
// wcg   : [J][L]        = 512
// w1g   : [J][L]        = 512
// Ag    : [J] (+pad)    = 16
// best  : [J][B][L]     = 262144
// conf  : [B]           = 512
// partial:[64][B][I]    = 1048576
// bpart : [2][J][B][L]  = 524288
// stats : [2][B][J][4]  = 32768

// ---------------------------------------------------------------- K0
__global__ __launch_bounds__(64) void k0_prep(const float* __restrict__ constants,
    const float* __restrict__ gammas, float* __restrict__ wcg,
    float* __restrict__ w1g, float* __restrict__ Ag)
{
  const int l = threadIdx.x;
  #pragma unroll
  for (int j = 0; j < J_; ++j) {
    float g = gammas[j*L_ + l];
    g = fminf(fmaxf(g, 0.f), 1.f);
    float c = constants[j*L_ + l];
    float w1 = 1.f - g;
    w1g[j*L_ + l] = w1;
    wcg[j*L_ + l] = w1 * c;
  }
  if (l < J_) {
    float a = 0.f;
    for (int c = 0; c < L_; ++c) {
      float g = gammas[l*L_ + c];
      g = fminf(fmaxf(g, 0.f), 1.f);
      float cc = constants[l*L_ + c];
      a += (1.f - g) * cc * cc;
    }
    Ag[l] = a;
  }
}

// ---------------------------------------------------------------- K12: half-W flash pass, software-pipelined staging
// (256,2): don't force VGPR below what the pipeline needs (R3's (256,4)
// caused 72 MB of scratch spills). Prefetch regs ~32 VGPR on top of R4's 76.
__global__ __launch_bounds__(256, 2) void k12_fused(const float* __restrict__ wm,
    const float* __restrict__ wcg, const float* __restrict__ w1g,
    const float* __restrict__ Ag, float* __restrict__ bpart, float* __restrict__ stats)
{
  __shared__ __align__(16) float xs[128 * 68];   // 34816 B
  __shared__ __align__(16) float es[J_ * 128];   // 4096 B
  __shared__ float redA[4][4], redB[4][4];
  __shared__ float bcast[J_];

  const int tid = threadIdx.x;
  const int b = blockIdx.x, h = blockIdx.y;
  const int lane = tid & 63, wv = tid >> 6;
  const int w = tid & 127;
  const int jh = tid >> 7;
  const int jbase = __builtin_amdgcn_readfirstlane(jh << 2);
  const int lq = tid & 15, wsl = tid >> 4;

  float accb[J_][4];
  #pragma unroll
  for (int j = 0; j < J_; ++j)
    #pragma unroll
    for (int q = 0; q < 4; ++q) accb[j][q] = 0.f;
  float esum[4], msum[4], m0[4];
  #pragma unroll
  for (int jj = 0; jj < 4; ++jj) { esum[jj] = 0.f; msum[jj] = 0.f; }

  const float* wmb = wm + (size_t)b * (W_*L_) + (size_t)h * (512*L_);

  // ---- prologue: stage chunk 0
  float4 pf[8];
  {
    const float4* src = (const float4*)wmb;
    #pragma unroll
    for (int k = 0; k < 8; ++k) pf[k] = src[k*256 + tid];
    #pragma unroll
    for (int k = 0; k < 8; ++k) {
      int f = k*256 + tid;
      *(float4*)&xs[(f >> 4)*68 + (f & 15)*4] = pf[k];
    }
  }
  __syncthreads();

  for (int ch = 0; ch < 4; ++ch) {
    // ---- issue prefetch of next chunk (waited only at the ds_write below,
    // i.e. after a full chunk of compute — latency hidden)
    if (ch < 3) {
      const float4* nsrc = (const float4*)(wmb + (ch+1) * (128*L_));
      #pragma unroll
      for (int k = 0; k < 8; ++k) pf[k] = nsrc[k*256 + tid];
    }

    // ---- score: thread owns (w, j = jbase..jbase+3)
    float a1[4], a2[4];
    #pragma unroll
    for (int jj = 0; jj < 4; ++jj) { a1[jj] = 0.f; a2[jj] = 0.f; }
    #pragma unroll
    for (int c = 0; c < 16; ++c) {
      float4 x = *(const float4*)&xs[w*68 + c*4];
      float4 xq;
      xq.x = x.x*x.x; xq.y = x.y*x.y; xq.z = x.z*x.z; xq.w = x.w*x.w;
      #pragma unroll
      for (int jj = 0; jj < 4; ++jj) {
        float4 wc4 = *(const float4*)(wcg + (jbase+jj)*L_ + c*4);   // uniform -> s_load
        float4 w14 = *(const float4*)(w1g + (jbase+jj)*L_ + c*4);
        a1[jj] = fmaf(wc4.x, x.x, a1[jj]);
        a1[jj] = fmaf(wc4.y, x.y, a1[jj]);
        a1[jj] = fmaf(wc4.z, x.z, a1[jj]);
        a1[jj] = fmaf(wc4.w, x.w, a1[jj]);
        a2[jj] = fmaf(w14.x, xq.x, a2[jj]);
        a2[jj] = fmaf(w14.y, xq.y, a2[jj]);
        a2[jj] = fmaf(w14.z, xq.z, a2[jj]);
        a2[jj] = fmaf(w14.w, xq.w, a2[jj]);
      }
    }
    float s[4];
    #pragma unroll
    for (int jj = 0; jj < 4; ++jj)
      s[jj] = Ag[jbase+jj] - 2.f*a1[jj] + a2[jj];

    if (ch == 0) {
      #pragma unroll
      for (int jj = 0; jj < 4; ++jj) {
        float mn = s[jj];
        #pragma unroll
        for (int off = 1; off < 64; off <<= 1)
          mn = fminf(mn, __shfl_xor(mn, off));
        if (lane == 0) redA[wv][jj] = mn;
      }
      __syncthreads();
      if (tid < J_) {
        int jj = tid & 3;
        bcast[tid] = (tid < 4) ? fminf(redA[0][jj], redA[1][jj])
                               : fminf(redA[2][jj], redA[3][jj]);
      }
      __syncthreads();
      #pragma unroll
      for (int jj = 0; jj < 4; ++jj) m0[jj] = bcast[jbase+jj];
    }

    #pragma unroll
    for (int jj = 0; jj < 4; ++jj) {
      float e = __expf(m0[jj] - s[jj]);
      esum[jj] += e;
      msum[jj] = fmaf(e, s[jj], msum[jj]);
      es[(jbase+jj)*128 + w] = e;
    }
    __syncthreads();   // es ready

    // ---- accumulate partial best
    #pragma unroll
    for (int tg = 0; tg < 2; ++tg) {
      float4 x[4];
      #pragma unroll
      for (int t = 0; t < 4; ++t)
        x[t] = *(const float4*)&xs[(wsl*8 + tg*4 + t)*68 + lq*4];
      #pragma unroll
      for (int j = 0; j < J_; ++j) {
        float4 e4 = *(const float4*)&es[j*128 + wsl*8 + tg*4];
        accb[j][0] = fmaf(e4.x, x[0].x, accb[j][0]);
        accb[j][1] = fmaf(e4.x, x[0].y, accb[j][1]);
        accb[j][2] = fmaf(e4.x, x[0].z, accb[j][2]);
        accb[j][3] = fmaf(e4.x, x[0].w, accb[j][3]);
        accb[j][0] = fmaf(e4.y, x[1].x, accb[j][0]);
        accb[j][1] = fmaf(e4.y, x[1].y, accb[j][1]);
        accb[j][2] = fmaf(e4.y, x[1].z, accb[j][2]);
        accb[j][3] = fmaf(e4.y, x[1].w, accb[j][3]);
        accb[j][0] = fmaf(e4.z, x[2].x, accb[j][0]);
        accb[j][1] = fmaf(e4.z, x[2].y, accb[j][1]);
        accb[j][2] = fmaf(e4.z, x[2].z, accb[j][2]);
        accb[j][3] = fmaf(e4.z, x[2].w, accb[j][3]);
        accb[j][0] = fmaf(e4.w, x[3].x, accb[j][0]);
        accb[j][1] = fmaf(e4.w, x[3].y, accb[j][1]);
        accb[j][2] = fmaf(e4.w, x[3].z, accb[j][2]);
        accb[j][3] = fmaf(e4.w, x[3].w, accb[j][3]);
      }
    }
    __syncthreads();   // all xs/es reads done -> safe to overwrite xs

    if (ch < 3) {
      #pragma unroll
      for (int k = 0; k < 8; ++k) {
        int f = k*256 + tid;
        *(float4*)&xs[(f >> 4)*68 + (f & 15)*4] = pf[k];
      }
      __syncthreads();   // xs ready for next chunk
    }
  }

  // ---- block-reduce esum/msum; write stats
  #pragma unroll
  for (int jj = 0; jj < 4; ++jj) {
    float e = esum[jj], m = msum[jj];
    #pragma unroll
    for (int off = 1; off < 64; off <<= 1) {
      e += __shfl_xor(e, off);
      m += __shfl_xor(m, off);
    }
    if (lane == 0) { redA[wv][jj] = e; redB[wv][jj] = m; }
  }
  __syncthreads();
  if (tid < J_) {
    int jj = tid & 3;
    float E = (tid < 4) ? redA[0][jj] + redA[1][jj] : redA[2][jj] + redA[3][jj];
    float M = (tid < 4) ? redB[0][jj] + redB[1][jj] : redB[2][jj] + redB[3][jj];
    float* st = stats + (((size_t)h*B_ + b)*J_ + tid)*4;
    st[0] = bcast[tid]; st[1] = E; st[2] = M;
  }

  // ---- reduce accb over 16 w-slots (reuse xs)
  #pragma unroll
  for (int j = 0; j < J_; ++j)
    *(float4*)&xs[((wsl*J_ + j)*16 + lq)*4] = *(float4*)accb[j];
  __syncthreads();
  if (tid < J_*16) {
    int j = tid >> 4, q = tid & 15;
    float4 sum = make_float4(0.f, 0.f, 0.f, 0.f);
    #pragma unroll
    for (int s2 = 0; s2 < 16; ++s2) {
      float4 p = *(const float4*)&xs[((s2*J_ + j)*16 + q)*4];
      sum.x += p.x; sum.y += p.y; sum.z += p.z; sum.w += p.w;
    }
    *(float4*)&bpart[(((size_t)h*J_ + j)*B_ + b)*L_ + q*4] = sum;
  }
}

// ---------------------------------------------------------------- K2b: combine halves
__global__ __launch_bounds__(128) void k2b_combine(const float* __restrict__ bpart,
    const float* __restrict__ stats, float* __restrict__ best, float* __restrict__ conf)
{
  __shared__ float mred[J_];
  const int b = blockIdx.x, tid = threadIdx.x;
  const int j = tid >> 4, q = tid & 15;
  const float* st0 = stats + ((size_t)b*J_ + j)*4;
  const float* st1 = stats + (((size_t)B_ + b)*J_ + j)*4;
  float m0a = st0[0], E0 = st0[1], M0 = st0[2];
  float m0b = st1[0], E1 = st1[1], M1 = st1[2];
  float M = fminf(m0a, m0b);
  float s0 = __expf(M - m0a), s1 = __expf(M - m0b);
  float E = s0*E0 + s1*E1;
  float inv = 1.f / E;
  float4 p0 = *(const float4*)&bpart[((size_t)j*B_ + b)*L_ + q*4];
  float4 p1 = *(const float4*)&bpart[(((size_t)J_ + j)*B_ + b)*L_ + q*4];
  float4 o;
  o.x = (s0*p0.x + s1*p1.x) * inv;
  o.y = (s0*p0.y + s1*p1.y) * inv;
  o.z = (s0*p0.z + s1*p1.z) * inv;
  o.w = (s0*p0.w + s1*p1.w) * inv;
  *(float4*)&best[((size_t)j*B_ + b)*L_ + q*4] = o;
  if (q == 0) mred[j] = (s0*M0 + s1*M1) * inv;
  __syncthreads();
  if (tid == 0) {
    float mq = 0.f;
    #pragma unroll
    for (int jj = 0; jj < J_; ++jj) mq += mred[jj];
    conf[b] = __expf(-mq);
  }
}

// ---------------------------------------------------------------- K3: slot path, 4-way b ILP, no max-stabilizer
// softmax is shift-invariant; logits = best.sw + b ~ N(0,~1), |logit| << 88,
// so raw exp cannot overflow -> drop the dependent max-reduction entirely.
__global__ __launch_bounds__(256) void k3_slot(const float* __restrict__ slot_w,
    const float* __restrict__ slot_b, const float* __restrict__ best,
    float* __restrict__ partial)
{
  const int bx = blockIdx.y;            // (j, lgroup)
  const int j = bx >> 3, lg = bx & 7;
  const int bc = blockIdx.x;            // b-chunk fast dim
  const int tid = threadIdx.x;
  const int wv = tid >> 6, lane = tid & 63;
  const int l2 = lane >> 5, i = lane & 31;
  const int l = lg*8 + wv*2 + l2;
  const int r = l*I_ + i;

  const float* swr = slot_w + ((size_t)j*(L_*I_) + r) * L_;
  float sw[L_];
  #pragma unroll
  for (int c = 0; c < 16; ++c) {
    float4 t = ((const float4*)swr)[c];
    sw[c*4+0] = t.x; sw[c*4+1] = t.y; sw[c*4+2] = t.z; sw[c*4+3] = t.w;
  }
  const float sb = slot_b[j*(L_*I_) + r];
  const float* bestj = best + (size_t)j * B_ * L_;
  float* pout = partial + (size_t)bx * (B_*I_);
  const int lidx = lg*8 + wv*2;

  for (int bi = 0; bi < 32; bi += 4) {
    const int b0 = bc*32 + bi;
    const float* bw[4];
    #pragma unroll
    for (int u = 0; u < 4; ++u) bw[u] = bestj + (size_t)(b0+u) * L_;  // uniform -> s_load
    float pa[4], pb[4];
    #pragma unroll
    for (int u = 0; u < 4; ++u) { pa[u] = sb; pb[u] = 0.f; }
    #pragma unroll
    for (int c = 0; c < L_; c += 2) {
      #pragma unroll
      for (int u = 0; u < 4; ++u) {
        pa[u] = fmaf(bw[u][c+0], sw[c+0], pa[u]);
        pb[u] = fmaf(bw[u][c+1], sw[c+1], pb[u]);
      }
    }
    float e[4], sm[4];
    #pragma unroll
    for (int u = 0; u < 4; ++u) { e[u] = __expf(pa[u] + pb[u]); sm[u] = e[u]; }
    #pragma unroll
    for (int mask = 16; mask; mask >>= 1)
      #pragma unroll
      for (int u = 0; u < 4; ++u) sm[u] += __shfl_xor(sm[u], mask);
    float cv[4];
    #pragma unroll
    for (int u = 0; u < 4; ++u) {
      float bv = l2 ? bw[u][lidx+1] : bw[u][lidx];
      cv[u] = (e[u] / sm[u]) * bv;
    }
    #pragma unroll
    for (int u = 0; u < 4; ++u) cv[u] += __shfl_xor(cv[u], 32);
    if (l2 == 0) {
      #pragma unroll
      for (int u = 0; u < 4; ++u)
        pout[(size_t)(b0+u)*I_ + i] = cv[u];
    }
  }
}

// ---------------------------------------------------------------- K4: reduce + body + head + confidence
__global__ __launch_bounds__(128) void k4_head(const float* __restrict__ partial,
    const float* __restrict__ best, const float* __restrict__ gammas,
    const float* __restrict__ body_w, const float* __restrict__ body_b,
    const float* __restrict__ head_w, const float* __restrict__ head_b,
    const float* __restrict__ conf, float* __restrict__ out)
{
  __shared__ float gavg[J_];
  __shared__ float cvred[4][I_];
  __shared__ float cvf[I_];
  const int b = blockIdx.x, tid = threadIdx.x;
  const int i = tid & 31, q = tid >> 5;   // q in 0..3
  if (tid < J_) {
    float gsum = 0.f;
    for (int l = 0; l < L_; ++l) {
      float g = gammas[tid*L_ + l];
      gsum += fminf(fmaxf(g, 0.f), 1.f);
    }
    gavg[tid] = gsum * (1.f / L_);
  }
  __syncthreads();

  float acc = 0.f;
  for (int s = q; s < 64; s += 4)
    acc += partial[((size_t)s*B_ + b)*I_ + i];

  #pragma unroll
  for (int u = 0; u < 2; ++u) {
    const int j = q + u*4;
    const float* bwv  = best + ((size_t)j*B_ + b)*L_;
    const float* wrow = body_w + (size_t)(j*I_ + i)*L_;
    float d0 = body_b[j*I_ + i], d1 = 0.f, d2 = 0.f, d3 = 0.f;
    #pragma unroll
    for (int c = 0; c < L_; c += 4) {
      d0 = fmaf(bwv[c+0], wrow[c+0], d0);
      d1 = fmaf(bwv[c+1], wrow[c+1], d1);
      d2 = fmaf(bwv[c+2], wrow[c+2], d2);
      d3 = fmaf(bwv[c+3], wrow[c+3], d3);
    }
    acc = fmaf(gavg[j], (d0 + d1) + (d2 + d3), acc);
  }
  cvred[q][i] = acc;
  __syncthreads();
  if (tid < I_)
    cvf[i] = cvred[0][i] + cvred[1][i] + cvred[2][i] + cvred[3][i];
  __syncthreads();
  float oacc = head_b[tid];
  #pragma unroll
  for (int i2 = 0; i2 < I_; ++i2) oacc = fmaf(cvf[i2], head_w[tid*I_ + i2], oacc);
  out[(size_t)b*O_ + tid] = conf[b] * oacc;
}

extern "C" void kernel_launch(void* const* d_in, const int* in_sizes, int n_in,
                              void* d_out, int out_size, void* d_ws, size_t ws_size,
                              hipStream_t stream) {
  const float* wm        = (const float*)d_in[0];
  const float* constants = (const float*)d_in[1];
  const float* gammas    = (const float*)d_in[2];
  const float* body_w    = (const float*)d_in[3];
  const float* body_b    = (const float*)d_in[4];
  const float* slot_w    = (const float*)d_in[5];
  const float* slot_b    = (const float*)d_in[6];
  const float* head_w    = (const float*)d_in[7];
  const float* head_b    = (const float*)d_in[8];
  float* out = (float*)d_out;

  float* ws      = (float*)d_ws;
  float* wcg     = ws;
  float* w1g     = wcg + J_*L_;
  float* Ag      = w1g + J_*L_;
  float* best    = Ag + 16;
  float* conf    = best + (size_t)J_*B_*L_;
  float* partial = conf + B_;
  float* bpart   = partial + (size_t)64*B_*I_;
  float* stats   = bpart + (size_t)2*J_*B_*L_;

  hipLaunchKernelGGL(k0_prep, dim3(1), dim3(64), 0, stream,
                     constants, gammas, wcg, w1g, Ag);
  hipLaunchKernelGGL(k12_fused, dim3(B_, 2), dim3(256), 0, stream,
                     wm, wcg, w1g, Ag, bpart, stats);
  hipLaunchKernelGGL(k2b_combine, dim3(B_), dim3(128), 0, stream,
                     bpart, stats, best, conf);
  hipLaunchKernelGGL(k3_slot, dim3(16, 64), dim3(256), 0, stream,
                     slot_w, slot_b, best, partial);
  hipLaunchKernelGGL(k4_head, dim3(B_), dim3(128), 0, stream,
                     partial, best, gammas, body_w, body_b, head_w, head_b, conf, out);
}

// Round 6
// 284.030 us; speedup vs baseline: 1.0806x; 1.0806x over previous
//
#include <hip/hip_runtime.h>
#include <cstdint>
#include <cstddef>

#define B_ 512
#define W_ 1024
#define L_ 64
#define J_ 8
#define I_ 32
#define O_ 128

// ws layout (floats):
// wcg   : [J][L]        = 512
// w1g   : [J][L]        = 512
// Ag    : [J] (+pad)    = 16
// best  : [J][B][L]     = 262144
// conf  : [B]           = 512
// partial:[64][B][I]    = 1048576
// bpart : [2][J][B][L]  = 524288
// stats : [2][B][J][4]  = 32768

typedef const __attribute__((address_space(1))) void* gas_ptr;
typedef __attribute__((address_space(3))) void* las_ptr;

// ---------------------------------------------------------------- K0
__global__ __launch_bounds__(64) void k0_prep(const float* __restrict__ constants,
    const float* __restrict__ gammas, float* __restrict__ wcg,
    float* __restrict__ w1g, float* __restrict__ Ag)
{
  const int l = threadIdx.x;
  #pragma unroll
  for (int j = 0; j < J_; ++j) {
    float g = gammas[j*L_ + l];
    g = fminf(fmaxf(g, 0.f), 1.f);
    float c = constants[j*L_ + l];
    float w1 = 1.f - g;
    w1g[j*L_ + l] = w1;
    wcg[j*L_ + l] = w1 * c;
  }
  if (l < J_) {
    float a = 0.f;
    for (int c = 0; c < L_; ++c) {
      float g = gammas[l*L_ + c];
      g = fminf(fmaxf(g, 0.f), 1.f);
      float cc = constants[l*L_ + c];
      a += (1.f - g) * cc * cc;
    }
    Ag[l] = a;
  }
}

// ---------------------------------------------------------------- K12: 64-row double-buffered chunks,
// async global->LDS staging (global_load_lds, zero staging VGPRs — R5's
// register prefetch spilled 100 MB to scratch). XOR-swizzled rows
// (col^ (row&15)) replace padding: DMA needs lane-contiguous LDS.
// Each wave owns j-pair {2wv,2wv+1} over all 64 rows: m0/E/M are pure
// shuffle reductions. 2 barriers/chunk; vmcnt drain at es-barrier lands
// a full score phase after issue -> latency hidden.
__global__ __launch_bounds__(256, 2) void k12_fused(const float* __restrict__ wm,
    const float* __restrict__ wcg, const float* __restrict__ w1g,
    const float* __restrict__ Ag, float* __restrict__ bpart, float* __restrict__ stats)
{
  __shared__ __align__(16) float xs[2][64 * 64];   // 32768 B
  __shared__ __align__(16) float es[J_ * 64];      // 2048 B

  const int tid = threadIdx.x;
  const int b = blockIdx.x, h = blockIdx.y;
  const int lane = tid & 63;
  const int wvu = __builtin_amdgcn_readfirstlane(tid >> 6);  // wave id (uniform)
  const int j0  = wvu * 2;                                   // this wave's j-pair
  const int lq = tid & 15, wsl = tid >> 4;                   // accum mapping
  const int wm15 = lane & 15;                                // score swizzle key
  const int rl = lane >> 4, pcg = lane & 15;                 // staging decomposition

  const float* wmb = wm + (size_t)b * (W_*L_) + (size_t)h * (512*L_);

  float accb[J_][4];
  #pragma unroll
  for (int j = 0; j < J_; ++j)
    #pragma unroll
    for (int q = 0; q < 4; ++q) accb[j][q] = 0.f;
  float esum[2] = {0.f, 0.f}, msum[2] = {0.f, 0.f}, m0v[2];

  // ---- stage chunk 0 into buffer 0
  {
    const float* csrc = wmb;
    #pragma unroll
    for (int k = 0; k < 4; ++k) {
      const int grow = wvu*16 + k*4 + rl;
      const int lcg  = pcg ^ (k*4 + rl);         // (grow&15) == k*4+rl
      __builtin_amdgcn_global_load_lds(
          (gas_ptr)(csrc + grow*64 + lcg*4),
          (las_ptr)&xs[0][(wvu*16 + k*4)*64], 16, 0, 0);
    }
  }
  __syncthreads();   // compiler drains vmcnt(0) here

  for (int ch = 0; ch < 8; ++ch) {
    const float* xb = &xs[ch & 1][0];

    // ---- issue async staging of next chunk into the other buffer
    if (ch < 7) {
      const float* csrc = wmb + (ch+1) * (64*L_);
      float* ldst = &xs[(ch+1) & 1][0];
      #pragma unroll
      for (int k = 0; k < 4; ++k) {
        const int grow = wvu*16 + k*4 + rl;
        const int lcg  = pcg ^ (k*4 + rl);
        __builtin_amdgcn_global_load_lds(
            (gas_ptr)(csrc + grow*64 + lcg*4),
            (las_ptr)(ldst + (wvu*16 + k*4)*64), 16, 0, 0);
      }
    }

    // ---- score: lane owns row w=lane, wave owns j-pair
    float a10 = 0.f, a11 = 0.f, a20 = 0.f, a21 = 0.f;
    #pragma unroll
    for (int c = 0; c < 16; ++c) {
      const int col = c ^ wm15;
      float4 x = *(const float4*)&xb[lane*64 + col*4];
      float4 xq;
      xq.x = x.x*x.x; xq.y = x.y*x.y; xq.z = x.z*x.z; xq.w = x.w*x.w;
      float4 wc0 = *(const float4*)(wcg + (j0  )*L_ + c*4);   // scalar (j0 uniform)
      float4 wc1 = *(const float4*)(wcg + (j0+1)*L_ + c*4);
      float4 w10 = *(const float4*)(w1g + (j0  )*L_ + c*4);
      float4 w11 = *(const float4*)(w1g + (j0+1)*L_ + c*4);
      a10 = fmaf(wc0.x, x.x, a10); a10 = fmaf(wc0.y, x.y, a10);
      a10 = fmaf(wc0.z, x.z, a10); a10 = fmaf(wc0.w, x.w, a10);
      a11 = fmaf(wc1.x, x.x, a11); a11 = fmaf(wc1.y, x.y, a11);
      a11 = fmaf(wc1.z, x.z, a11); a11 = fmaf(wc1.w, x.w, a11);
      a20 = fmaf(w10.x, xq.x, a20); a20 = fmaf(w10.y, xq.y, a20);
      a20 = fmaf(w10.z, xq.z, a20); a20 = fmaf(w10.w, xq.w, a20);
      a21 = fmaf(w11.x, xq.x, a21); a21 = fmaf(w11.y, xq.y, a21);
      a21 = fmaf(w11.z, xq.z, a21); a21 = fmaf(w11.w, xq.w, a21);
    }
    float s0 = Ag[j0]   - 2.f*a10 + a20;
    float s1 = Ag[j0+1] - 2.f*a11 + a21;

    if (ch == 0) {   // stabilizer: pure wave-reduce (scores >= 0, chunk-0 min safe)
      float mn0 = s0, mn1 = s1;
      #pragma unroll
      for (int off = 1; off < 64; off <<= 1) {
        mn0 = fminf(mn0, __shfl_xor(mn0, off));
        mn1 = fminf(mn1, __shfl_xor(mn1, off));
      }
      m0v[0] = mn0; m0v[1] = mn1;
    }

    float e0 = __expf(m0v[0] - s0);
    float e1 = __expf(m0v[1] - s1);
    esum[0] += e0; msum[0] = fmaf(e0, s0, msum[0]);
    esum[1] += e1; msum[1] = fmaf(e1, s1, msum[1]);
    es[(j0  )*64 + lane] = e0;
    es[(j0+1)*64 + lane] = e1;
    __syncthreads();   // es ready; vmcnt(0) drain lands here (hidden by score)

    // ---- accumulate partial best: thread (lq, wsl) owns 16B slot lq, rows wsl*4..+3
    float4 x4[4];
    #pragma unroll
    for (int t = 0; t < 4; ++t) {
      const int w2 = wsl*4 + t;
      const int col = lq ^ (w2 & 15);
      x4[t] = *(const float4*)&xb[w2*64 + col*4];
    }
    #pragma unroll
    for (int j = 0; j < J_; ++j) {
      float4 e4 = *(const float4*)&es[j*64 + wsl*4];   // 16-lane broadcast
      accb[j][0] = fmaf(e4.x, x4[0].x, accb[j][0]);
      accb[j][1] = fmaf(e4.x, x4[0].y, accb[j][1]);
      accb[j][2] = fmaf(e4.x, x4[0].z, accb[j][2]);
      accb[j][3] = fmaf(e4.x, x4[0].w, accb[j][3]);
      accb[j][0] = fmaf(e4.y, x4[1].x, accb[j][0]);
      accb[j][1] = fmaf(e4.y, x4[1].y, accb[j][1]);
      accb[j][2] = fmaf(e4.y, x4[1].z, accb[j][2]);
      accb[j][3] = fmaf(e4.y, x4[1].w, accb[j][3]);
      accb[j][0] = fmaf(e4.z, x4[2].x, accb[j][0]);
      accb[j][1] = fmaf(e4.z, x4[2].y, accb[j][1]);
      accb[j][2] = fmaf(e4.z, x4[2].z, accb[j][2]);
      accb[j][3] = fmaf(e4.z, x4[2].w, accb[j][3]);
      accb[j][0] = fmaf(e4.w, x4[3].x, accb[j][0]);
      accb[j][1] = fmaf(e4.w, x4[3].y, accb[j][1]);
      accb[j][2] = fmaf(e4.w, x4[3].z, accb[j][2]);
      accb[j][3] = fmaf(e4.w, x4[3].w, accb[j][3]);
    }
    __syncthreads();   // xb reads done -> buffer free for ch+2 staging
  }

  // ---- stats: wave-local reduce, lane 0 writes both j's
  #pragma unroll
  for (int u = 0; u < 2; ++u) {
    float e = esum[u], m = msum[u];
    #pragma unroll
    for (int off = 1; off < 64; off <<= 1) {
      e += __shfl_xor(e, off);
      m += __shfl_xor(m, off);
    }
    if (lane == 0) {
      float* st = stats + (((size_t)h*B_ + b)*J_ + (j0+u))*4;
      st[0] = m0v[u]; st[1] = e; st[2] = m;
    }
  }

  // ---- reduce accb over the 16 w-slots (reuse xs; last loop barrier protects)
  float* xsf = &xs[0][0];
  #pragma unroll
  for (int j = 0; j < J_; ++j)
    *(float4*)&xsf[((wsl*J_ + j)*16 + lq)*4] = *(float4*)accb[j];
  __syncthreads();
  if (tid < J_*16) {
    int j = tid >> 4, q = tid & 15;
    float4 sum = make_float4(0.f, 0.f, 0.f, 0.f);
    #pragma unroll
    for (int s2 = 0; s2 < 16; ++s2) {
      float4 p = *(const float4*)&xsf[((s2*J_ + j)*16 + q)*4];
      sum.x += p.x; sum.y += p.y; sum.z += p.z; sum.w += p.w;
    }
    *(float4*)&bpart[(((size_t)h*J_ + j)*B_ + b)*L_ + q*4] = sum;
  }
}

// ---------------------------------------------------------------- K2b: combine halves
__global__ __launch_bounds__(128) void k2b_combine(const float* __restrict__ bpart,
    const float* __restrict__ stats, float* __restrict__ best, float* __restrict__ conf)
{
  __shared__ float mred[J_];
  const int b = blockIdx.x, tid = threadIdx.x;
  const int j = tid >> 4, q = tid & 15;
  const float* st0 = stats + ((size_t)b*J_ + j)*4;
  const float* st1 = stats + (((size_t)B_ + b)*J_ + j)*4;
  float m0a = st0[0], E0 = st0[1], M0 = st0[2];
  float m0b = st1[0], E1 = st1[1], M1 = st1[2];
  float M = fminf(m0a, m0b);
  float s0 = __expf(M - m0a), s1 = __expf(M - m0b);
  float E = s0*E0 + s1*E1;
  float inv = 1.f / E;
  float4 p0 = *(const float4*)&bpart[((size_t)j*B_ + b)*L_ + q*4];
  float4 p1 = *(const float4*)&bpart[(((size_t)J_ + j)*B_ + b)*L_ + q*4];
  float4 o;
  o.x = (s0*p0.x + s1*p1.x) * inv;
  o.y = (s0*p0.y + s1*p1.y) * inv;
  o.z = (s0*p0.z + s1*p1.z) * inv;
  o.w = (s0*p0.w + s1*p1.w) * inv;
  *(float4*)&best[((size_t)j*B_ + b)*L_ + q*4] = o;
  if (q == 0) mred[j] = (s0*M0 + s1*M1) * inv;
  __syncthreads();
  if (tid == 0) {
    float mq = 0.f;
    #pragma unroll
    for (int jj = 0; jj < J_; ++jj) mq += mred[jj];
    conf[b] = __expf(-mq);
  }
}

// ---------------------------------------------------------------- K3: slot path, 4-way b ILP, no max-stabilizer
__global__ __launch_bounds__(256) void k3_slot(const float* __restrict__ slot_w,
    const float* __restrict__ slot_b, const float* __restrict__ best,
    float* __restrict__ partial)
{
  const int bx = blockIdx.y;            // (j, lgroup)
  const int j = bx >> 3, lg = bx & 7;
  const int bc = blockIdx.x;            // b-chunk fast dim -> L2 reuse
  const int tid = threadIdx.x;
  const int wv = tid >> 6, lane = tid & 63;
  const int l2 = lane >> 5, i = lane & 31;
  const int l = lg*8 + wv*2 + l2;
  const int r = l*I_ + i;

  const float* swr = slot_w + ((size_t)j*(L_*I_) + r) * L_;
  float sw[L_];
  #pragma unroll
  for (int c = 0; c < 16; ++c) {
    float4 t = ((const float4*)swr)[c];
    sw[c*4+0] = t.x; sw[c*4+1] = t.y; sw[c*4+2] = t.z; sw[c*4+3] = t.w;
  }
  const float sb = slot_b[j*(L_*I_) + r];
  const float* bestj = best + (size_t)j * B_ * L_;
  float* pout = partial + (size_t)bx * (B_*I_);
  const int lidx = lg*8 + wv*2;

  for (int bi = 0; bi < 32; bi += 4) {
    const int b0 = bc*32 + bi;
    const float* bw[4];
    #pragma unroll
    for (int u = 0; u < 4; ++u) bw[u] = bestj + (size_t)(b0+u) * L_;  // uniform -> s_load
    float pa[4], pb[4];
    #pragma unroll
    for (int u = 0; u < 4; ++u) { pa[u] = sb; pb[u] = 0.f; }
    #pragma unroll
    for (int c = 0; c < L_; c += 2) {
      #pragma unroll
      for (int u = 0; u < 4; ++u) {
        pa[u] = fmaf(bw[u][c+0], sw[c+0], pa[u]);
        pb[u] = fmaf(bw[u][c+1], sw[c+1], pb[u]);
      }
    }
    float e[4], sm[4];
    #pragma unroll
    for (int u = 0; u < 4; ++u) { e[u] = __expf(pa[u] + pb[u]); sm[u] = e[u]; }
    #pragma unroll
    for (int mask = 16; mask; mask >>= 1)
      #pragma unroll
      for (int u = 0; u < 4; ++u) sm[u] += __shfl_xor(sm[u], mask);
    float cv[4];
    #pragma unroll
    for (int u = 0; u < 4; ++u) {
      float bv = l2 ? bw[u][lidx+1] : bw[u][lidx];
      cv[u] = (e[u] / sm[u]) * bv;
    }
    #pragma unroll
    for (int u = 0; u < 4; ++u) cv[u] += __shfl_xor(cv[u], 32);
    if (l2 == 0) {
      #pragma unroll
      for (int u = 0; u < 4; ++u)
        pout[(size_t)(b0+u)*I_ + i] = cv[u];
    }
  }
}

// ---------------------------------------------------------------- K4: reduce + body + head + confidence
__global__ __launch_bounds__(128) void k4_head(const float* __restrict__ partial,
    const float* __restrict__ best, const float* __restrict__ gammas,
    const float* __restrict__ body_w, const float* __restrict__ body_b,
    const float* __restrict__ head_w, const float* __restrict__ head_b,
    const float* __restrict__ conf, float* __restrict__ out)
{
  __shared__ float gavg[J_];
  __shared__ float cvred[4][I_];
  __shared__ float cvf[I_];
  const int b = blockIdx.x, tid = threadIdx.x;
  const int i = tid & 31, q = tid >> 5;
  if (tid < J_) {
    float gsum = 0.f;
    for (int l = 0; l < L_; ++l) {
      float g = gammas[tid*L_ + l];
      gsum += fminf(fmaxf(g, 0.f), 1.f);
    }
    gavg[tid] = gsum * (1.f / L_);
  }
  __syncthreads();

  float acc = 0.f;
  for (int s = q; s < 64; s += 4)
    acc += partial[((size_t)s*B_ + b)*I_ + i];

  #pragma unroll
  for (int u = 0; u < 2; ++u) {
    const int j = q + u*4;
    const float* bwv  = best + ((size_t)j*B_ + b)*L_;
    const float* wrow = body_w + (size_t)(j*I_ + i)*L_;
    float d0 = body_b[j*I_ + i], d1 = 0.f, d2 = 0.f, d3 = 0.f;
    #pragma unroll
    for (int c = 0; c < L_; c += 4) {
      d0 = fmaf(bwv[c+0], wrow[c+0], d0);
      d1 = fmaf(bwv[c+1], wrow[c+1], d1);
      d2 = fmaf(bwv[c+2], wrow[c+2], d2);
      d3 = fmaf(bwv[c+3], wrow[c+3], d3);
    }
    acc = fmaf(gavg[j], (d0 + d1) + (d2 + d3), acc);
  }
  cvred[q][i] = acc;
  __syncthreads();
  if (tid < I_)
    cvf[i] = cvred[0][i] + cvred[1][i] + cvred[2][i] + cvred[3][i];
  __syncthreads();
  float oacc = head_b[tid];
  #pragma unroll
  for (int i2 = 0; i2 < I_; ++i2) oacc = fmaf(cvf[i2], head_w[tid*I_ + i2], oacc);
  out[(size_t)b*O_ + tid] = conf[b] * oacc;
}

extern "C" void kernel_launch(void* const* d_in, const int* in_sizes, int n_in,
                              void* d_out, int out_size, void* d_ws, size_t ws_size,
                              hipStream_t stream) {
  const float* wm        = (const float*)d_in[0];
  const float* constants = (const float*)d_in[1];
  const float* gammas    = (const float*)d_in[2];
  const float* body_w    = (const float*)d_in[3];
  const float* body_b    = (const float*)d_in[4];
  const float* slot_w    = (const float*)d_in[5];
  const float* slot_b    = (const float*)d_in[6];
  const float* head_w    = (const float*)d_in[7];
  const float* head_b    = (const float*)d_in[8];
  float* out = (float*)d_out;

  float* ws      = (float*)d_ws;
  float* wcg     = ws;
  float* w1g     = wcg + J_*L_;
  float* Ag      = w1g + J_*L_;
  float* best    = Ag + 16;
  float* conf    = best + (size_t)J_*B_*L_;
  float* partial = conf + B_;
  float* bpart   = partial + (size_t)64*B_*I_;
  float* stats   = bpart + (size_t)2*J_*B_*L_;

  hipLaunchKernelGGL(k0_prep, dim3(1), dim3(64), 0, stream,
                     constants, gammas, wcg, w1g, Ag);
  hipLaunchKernelGGL(k12_fused, dim3(B_, 2), dim3(256), 0, stream,
                     wm, wcg, w1g, Ag, bpart, stats);
  hipLaunchKernelGGL(k2b_combine, dim3(B_), dim3(128), 0, stream,
                     bpart, stats, best, conf);
  hipLaunchKernelGGL(k3_slot, dim3(16, 64), dim3(256), 0, stream,
                     slot_w, slot_b, best, partial);
  hipLaunchKernelGGL(k4_head, dim3(B_), dim3(128), 0, stream,
                     partial, best, gammas, body_w, body_b, head_w, head_b, conf, out);
}